// Round 1
// 317.305 us; speedup vs baseline: 1.0709x; 1.0709x over previous
//
#include <hip/hip_runtime.h>

typedef __attribute__((ext_vector_type(8))) __bf16 bf16x8;
typedef __attribute__((ext_vector_type(4))) float f32x4;
typedef __attribute__((ext_vector_type(4))) float f4;
typedef __attribute__((ext_vector_type(4))) unsigned short ushort4_t;

__device__ inline void gload16(const void* g, void* l) {
  __builtin_amdgcn_global_load_lds(
      (const __attribute__((address_space(1))) unsigned int*)g,
      (__attribute__((address_space(3))) unsigned int*)l, 16, 0, 0);
}

// ---------------------------------------------------------------- converts
__global__ void convert_bf16_k(const float* __restrict__ in, __bf16* __restrict__ out, int n8) {
  int i = blockIdx.x * blockDim.x + threadIdx.x;
  int stride = gridDim.x * blockDim.x;
  for (; i < n8; i += stride) {
    f4 a = ((const f4*)in)[2 * (long long)i];
    f4 b = ((const f4*)in)[2 * (long long)i + 1];
    bf16x8 o;
#pragma unroll
    for (int e = 0; e < 4; e++) { o[e] = (__bf16)a[e]; o[e + 4] = (__bf16)b[e]; }
    ((bf16x8*)out)[i] = o;
  }
}

__global__ void pack_bias_k(const float* __restrict__ bq, const float* __restrict__ bk,
                            const float* __restrict__ bv, float* __restrict__ out) {
  int i = blockIdx.x * 256 + threadIdx.x;
  if (i >= 3072) return;
  const float* src = (i < 1024) ? bq : (i < 2048) ? bk : bv;
  out[i] = src[i & 1023];
}

// W[k][n] fp32 -> Wt[n][k] bf16, 4 weights via z (Wq,Wk,Wv stacked = [3072][1024], Wo at +3M)
__global__ void transpose_w_k(const float* __restrict__ W0, const float* __restrict__ W1,
                              const float* __restrict__ W2, const float* __restrict__ W3,
                              __bf16* __restrict__ out) {
  int z = blockIdx.z;
  const float* W = (z == 0) ? W0 : (z == 1) ? W1 : (z == 2) ? W2 : W3;
  __bf16* O = out + (long long)z * 1048576;
  __shared__ float tile[32][33];
  int tx = threadIdx.x, ty = threadIdx.y;
  int n0 = blockIdx.x * 32, k0 = blockIdx.y * 32;
#pragma unroll
  for (int i = 0; i < 4; i++)
    tile[ty + i * 8][tx] = W[(long long)(k0 + ty + i * 8) * 1024 + n0 + tx];
  __syncthreads();
#pragma unroll
  for (int i = 0; i < 4; i++)
    O[(long long)(n0 + ty + i * 8) * 1024 + k0 + tx] = (__bf16)tile[tx][ty + i * 8];
}

// ---------------------------------------------------------------- GEMM: 256x256 tile, BK=64, 8-phase
// C[z] = A[z] (M x K row-major) @ Bt[z]^T (Bt = N x K row-major) + bias.
// 8 waves (2M x 4N), per-wave 128x64 output, acc[8][4] f32x4.
// LDS: A[2 parity][2 half][128x64] + B same = 128 KiB, XOR-swizzled (row&7)<<4.
// OUT: 0 = bf16 C, 1 = f32 C, 2 = fused QKV (cols<2048 -> C bf16 [.,2048],
//       Q-cols scaled; cols>=2048 -> V written TRANSPOSED into vt_out[b][d][t]).
// SWZ: 0 = generic bijective XCD swizzle (nwg%8==0)
//      1 = A-stripe: XCD q owns br in [8q,8q+8) x all bc (br fast) - requires gridDim.x==64
//      2 = packed causal triangle: XCD q = batch q, tri index -> (br,bc), bc<=br

#define ABUF(P, H) (lds + ((P) * 2 + (H)) * 8192)
#define BBUF(P, H) (lds + 32768 + ((P) * 2 + (H)) * 8192)

#define LOADA(P, MIB)                                                          \
  _Pragma("unroll") for (int mi = 0; mi < 4; mi++)                             \
      _Pragma("unroll") for (int kh = 0; kh < 2; kh++) {                       \
    int row = ((MIB) + mi) * 16 + ln15;                                        \
    int pb = (row * 128 + (kh * 32 + kq * 8) * 2) ^ ((row & 7) << 4);          \
    a[mi][kh] = *(const bf16x8*)((const char*)ABUF(P, wm) + pb);               \
  }

#define LOADB(P, NIB)                                                          \
  _Pragma("unroll") for (int ni = 0; ni < 2; ni++)                             \
      _Pragma("unroll") for (int kh = 0; kh < 2; kh++) {                       \
    int row = brow0 + ((NIB) + ni) * 16 + ln15;                                \
    int pb = (row * 128 + (kh * 32 + kq * 8) * 2) ^ ((row & 7) << 4);          \
    b[(NIB) + ni][kh] = *(const bf16x8*)((const char*)BBUF(P, bh) + pb);       \
  }

#define MFMAQ(MI0, NI0)                                                        \
  _Pragma("unroll") for (int mi = 0; mi < 4; mi++)                             \
      _Pragma("unroll") for (int ni = 0; ni < 2; ni++)                         \
          _Pragma("unroll") for (int kh = 0; kh < 2; kh++)                     \
              acc[(MI0) + mi][(NI0) + ni] =                                    \
      __builtin_amdgcn_mfma_f32_16x16x32_bf16(a[mi][kh], b[(NI0) + ni][kh],    \
                                              acc[(MI0) + mi][(NI0) + ni], 0, 0, 0);

#define FENCE asm volatile("" ::: "memory")

#define BARW                                           \
  FENCE;                                               \
  __builtin_amdgcn_s_barrier();                        \
  FENCE;                                               \
  __builtin_amdgcn_s_setprio(1);

#define ENDP                                           \
  __builtin_amdgcn_s_setprio(0);                       \
  FENCE;                                               \
  __builtin_amdgcn_s_barrier();                        \
  FENCE;

#define ENDPB                                          \
  __builtin_amdgcn_s_setprio(0);                       \
  asm volatile("s_waitcnt vmcnt(4)" ::: "memory");     \
  __builtin_amdgcn_s_barrier();                        \
  FENCE;

template <int OUT, int SWZ>
__global__ __launch_bounds__(512, 2) void gemm8(
    const __bf16* __restrict__ A0, int lda, long long sAz,
    const __bf16* __restrict__ B0, int ldb, long long sBz,
    void* __restrict__ C0v, int ldc, long long sCz,
    const float* __restrict__ bias0, int sBiasZ,
    float scale_z0, int k_tiles_base, int k_tiles_per_br,
    __bf16* __restrict__ vt_out) {
  int br, bc, z;
  {
    const int lin = (blockIdx.z * gridDim.y + blockIdx.y) * gridDim.x + blockIdx.x;
    if (SWZ == 1) {
      // A-stripe partitioning: XCD q -> br in [8q,8q+8), br fast within chunk
      // so a round (32 CUs) = 8 br x 4 bc: A-stripe 4MB + 4 B panels 2MB in L2.
      const int q = lin & 7, c = lin >> 3;
      br = q * 8 + (c & 7);
      bc = c >> 3;
      z = 0;
    } else if (SWZ == 2) {
      // packed lower triangle, one batch per XCD; c in [0,36) -> (br,bc) bc<=br
      const int q = lin & 7, c = lin >> 3;
      z = q;
      int b0 = (int)((sqrtf((float)(8 * c + 1)) - 1.0f) * 0.5f);
      int c0 = c - ((b0 * (b0 + 1)) >> 1);
      if (c0 < 0) { b0--; c0 = c - ((b0 * (b0 + 1)) >> 1); }
      if (c0 > b0) { b0++; c0 = c - ((b0 * (b0 + 1)) >> 1); }
      br = b0;
      bc = c0;
    } else {
      const int nbx = gridDim.x, nby = gridDim.y;
      const int nwg = nbx * nby * gridDim.z;
      const int cpx = nwg >> 3;
      const int swz = (lin & 7) * cpx + (lin >> 3);
      br = swz % nbx;
      const int tmp = swz / nbx;
      bc = tmp % nby;
      z = tmp / nby;
    }
  }
  const int kt = k_tiles_base + k_tiles_per_br * br;  // even, >= 2

  __shared__ __align__(16) __bf16 lds[65536];  // 128 KiB

  const int t = threadIdx.x, w = t >> 6, lane = t & 63;
  const int wm = w >> 2, wn = w & 3;
  const int ln15 = lane & 15, kq = lane >> 4;
  const int bh = wn >> 1, brow0 = (wn & 1) * 64;

  const __bf16* A = A0 + (long long)z * sAz + (long long)br * 256 * lda;
  const __bf16* B = B0 + (long long)z * sBz + (long long)bc * 256 * ldb;

  // pre-swizzled staging source coords (physical->logical, involution)
  int r0s[2], c0s[2];
#pragma unroll
  for (int i = 0; i < 2; i++) {
    int o = i * 8192 + t * 16;
    int lo = o ^ (((o >> 7) & 7) << 4);
    r0s[i] = lo >> 7;
    c0s[i] = (lo & 127) >> 1;
  }
  // hoisted per-thread source pointers (k-tile adds kc*64 only)
  const __bf16 *sA0[2], *sA1[2], *sB0[2], *sB1[2];
#pragma unroll
  for (int i = 0; i < 2; i++) {
    sA0[i] = A + (long long)r0s[i] * lda + c0s[i];
    sA1[i] = A + (long long)(r0s[i] + 128) * lda + c0s[i];
    sB0[i] = B + (long long)r0s[i] * ldb + c0s[i];
    sB1[i] = B + (long long)(r0s[i] + 128) * ldb + c0s[i];
  }

  auto stg = [&](const __bf16* const* src, __bf16* lbase, int ktile) {
    int kc = ktile < kt ? ktile : kt - 1;
#pragma unroll
    for (int i = 0; i < 2; i++)
      gload16(src[i] + kc * 64, lbase + i * 4096 + w * 512);
  };

  f32x4 acc[8][4] = {};
  bf16x8 a[4][2], b[4][2];

  // prologue: B(t0), A(t0), B(t1); wait oldest 8 -> A0,B0 resident, B1 in flight
  stg(sB0, BBUF(0, 0), 0);
  stg(sB1, BBUF(0, 1), 0);
  stg(sA0, ABUF(0, 0), 0);
  stg(sA1, ABUF(0, 1), 0);
  stg(sB0, BBUF(1, 0), 1);
  stg(sB1, BBUF(1, 1), 1);
  asm volatile("s_waitcnt vmcnt(4)" ::: "memory");
  __builtin_amdgcn_s_barrier();
  FENCE;

  for (int kk = 0; kk < kt; kk += 2) {
    // ---- tile kk (parity 0) ----
    LOADA(0, 0) LOADB(0, 0)
    stg(sA0, ABUF(1, 0), kk + 1);
    BARW MFMAQ(0, 0) ENDP
    LOADB(0, 2)
    stg(sA1, ABUF(1, 1), kk + 1);
    BARW MFMAQ(0, 2) ENDP
    LOADA(0, 4)
    stg(sB0, BBUF(0, 0), kk + 2);
    BARW MFMAQ(4, 2) ENDP
    stg(sB1, BBUF(0, 1), kk + 2);
    BARW MFMAQ(4, 0) ENDPB
    // ---- tile kk+1 (parity 1) ----
    LOADA(1, 0) LOADB(1, 0)
    stg(sA0, ABUF(0, 0), kk + 2);
    BARW MFMAQ(0, 0) ENDP
    LOADB(1, 2)
    stg(sA1, ABUF(0, 1), kk + 2);
    BARW MFMAQ(0, 2) ENDP
    LOADA(1, 4)
    stg(sB0, BBUF(1, 0), kk + 3);
    BARW MFMAQ(4, 2) ENDP
    stg(sB1, BBUF(1, 1), kk + 3);
    BARW MFMAQ(4, 0) ENDPB
  }

  // ---- epilogue ----
  const int row0 = br * 256 + wm * 128 + kq * 4;
  const int col0 = bc * 256 + wn * 64 + ln15;
  if (OUT == 2) {
    // fused QKV epilogue: Q (cc<1024, scaled) and K (1024<=cc<2048) -> C [.,ldc=2048];
    // V (cc>=2048) transposed into vt_out[b][d][t] as 4x-bf16 packed stores.
#pragma unroll
    for (int mi = 0; mi < 8; mi++) {
      const int rr = row0 + mi * 16;
#pragma unroll
      for (int ni = 0; ni < 4; ni++) {
        const int cc = col0 + ni * 16;
        const float bb = bias0[cc];
        if (cc < 2048) {
          const float s = (cc < 1024) ? scale_z0 : 1.0f;
#pragma unroll
          for (int j = 0; j < 4; j++)
            ((__bf16*)C0v)[(long long)(rr + j) * ldc + cc] =
                (__bf16)((acc[mi][ni][j] + bb) * s);
        } else {
          const int d = cc - 2048, bz = rr >> 11, t0 = rr & 2047;
          ushort4_t p;
#pragma unroll
          for (int j = 0; j < 4; j++) {
            union { __bf16 h; unsigned short u; } cv;
            cv.h = (__bf16)(acc[mi][ni][j] + bb);
            p[j] = cv.u;
          }
          *(ushort4_t*)(vt_out + (long long)bz * 2097152 + (long long)d * 2048 + t0) = p;
        }
      }
    }
  } else {
    const float scale = (z == 0) ? scale_z0 : 1.0f;
    const float* bias = bias0 ? (bias0 + (long long)z * sBiasZ) : nullptr;
#pragma unroll
    for (int mi = 0; mi < 8; mi++) {
#pragma unroll
      for (int ni = 0; ni < 4; ni++) {
        const int rr = row0 + mi * 16;
        const int cc = col0 + ni * 16;
        const float bb = bias ? bias[cc] : 0.0f;
#pragma unroll
        for (int j = 0; j < 4; j++) {
          float v = (acc[mi][ni][j] + bb) * scale;
          long long off = (long long)z * sCz + (long long)(rr + j) * ldc + cc;
          if (OUT == 1)
            ((float*)C0v)[off] = v;
          else
            ((__bf16*)C0v)[off] = (__bf16)v;
        }
      }
    }
  }
}

// ---------------------------------------------------------------- softmax (causal, in-place on S bf16)
__global__ __launch_bounds__(256) void softmax_rows(__bf16* __restrict__ S) {
  const int row = blockIdx.x;  // 0..16383 = b*2048 + i
  const int i = row & 2047;
  __bf16* s = S + (long long)row * 2048;
  const int Lpad = (i + 256) & ~255;  // round_up(i+1, 256): PV reads this far
  const int t = threadIdx.x;
  const int j0 = t * 8;
  const int wid = t >> 6, lane = t & 63;
  const bool active = j0 < Lpad;

  float v[8];
  float mymax = -3.0e38f;
  if (active) {
    bf16x8 x = *(const bf16x8*)(s + j0);
#pragma unroll
    for (int e = 0; e < 8; e++) {
      float f = (float)x[e];
      v[e] = ((j0 + e) <= i) ? f : -3.0e38f;
      mymax = fmaxf(mymax, v[e]);
    }
  }
  float mw = mymax;
#pragma unroll
  for (int o = 32; o >= 1; o >>= 1) mw = fmaxf(mw, __shfl_xor(mw, o));
  __shared__ float redm[4];
  __shared__ float reds[4];
  if (lane == 0) redm[wid] = mw;
  __syncthreads();
  const float m = fmaxf(fmaxf(redm[0], redm[1]), fmaxf(redm[2], redm[3]));

  float e8[8];
  float mysum = 0.0f;
  if (active) {
#pragma unroll
    for (int e = 0; e < 8; e++) {
      float ev = ((j0 + e) <= i) ? __expf(v[e] - m) : 0.0f;
      e8[e] = ev;
      mysum += ev;
    }
  } else {
#pragma unroll
    for (int e = 0; e < 8; e++) e8[e] = 0.0f;
  }
  float sw = mysum;
#pragma unroll
  for (int o = 32; o >= 1; o >>= 1) sw += __shfl_xor(sw, o);
  if (lane == 0) reds[wid] = sw;
  __syncthreads();
  const float l = reds[0] + reds[1] + reds[2] + reds[3];
  const float rl = 1.0f / l;
  if (active) {
    bf16x8 o;
#pragma unroll
    for (int e = 0; e < 8; e++) o[e] = (__bf16)(e8[e] * rl);
    *(bf16x8*)(s + j0) = o;
  }
}

// ---------------------------------------------------------------- launch
extern "C" void kernel_launch(void* const* d_in, const int* in_sizes, int n_in,
                              void* d_out, int out_size, void* d_ws, size_t ws_size,
                              hipStream_t stream) {
  const float* y  = (const float*)d_in[0];
  const float* Wq = (const float*)d_in[1];
  const float* bq = (const float*)d_in[2];
  const float* Wk = (const float*)d_in[3];
  const float* bk = (const float*)d_in[4];
  const float* Wv = (const float*)d_in[5];
  const float* bv = (const float*)d_in[6];
  const float* Wo = (const float*)d_in[7];
  const float* bo = (const float*)d_in[8];

  char* ws = (char*)d_ws;
  __bf16* Xb   = (__bf16*)(ws + 0);            // 16384x1024 bf16 X        (32 MiB) [ctx after QKV]
  __bf16* Wt   = (__bf16*)(ws + 33554432);     // 4 x [1024][1024] bf16 W^T (8 MiB)
  float*  bqkv = (float*)(ws + 41943040);      // 3x1024 fp32
  __bf16* QK   = (__bf16*)(ws + 41955328);     // [16384][2048] Q|K bf16   (64 MiB)
  __bf16* Vt   = (__bf16*)(ws + 109064192);    // 8 x [1024][2048] V^T     (32 MiB)
  __bf16* Sb   = (__bf16*)(ws + 142618624);    // 8 x 2048x2048 S/P (ends at 209,727,488)
  __bf16* ctx  = (__bf16*)(ws + 0);            // PV output reuses Xb region

  if (ws_size < 209727488u) return;

  convert_bf16_k<<<2048, 256, 0, stream>>>(y, Xb, 2097152);
  pack_bias_k<<<12, 256, 0, stream>>>(bq, bk, bv, bqkv);
  transpose_w_k<<<dim3(32, 32, 4), dim3(32, 8), 0, stream>>>(Wq, Wk, Wv, Wo, Wt);

  // Fused QKV projection: one N=3072 GEMM, A-stripe swizzle.
  // Q (scaled 1/32) and K -> QK [16384][2048]; V -> Vt[b][d][t] (pre-transposed).
  gemm8<2, 1><<<dim3(64, 12, 1), 512, 0, stream>>>(
      Xb, 1024, 0LL, Wt, 1024, 0LL,
      QK, 2048, 0LL, bqkv, 0, 0.03125f, 16, 0, Vt);

  // S = Q @ K^T per batch: packed lower-triangle launch (36 tiles x 8 batches)
  gemm8<0, 2><<<dim3(36, 1, 8), 512, 0, stream>>>(
      QK, 2048, 4194304LL, QK + 1024, 2048, 4194304LL,
      Sb, 2048, 4194304LL, nullptr, 0, 1.0f, 16, 0, nullptr);

  // causal softmax in place (zero-pads to 256-block edge)
  softmax_rows<<<16384, 256, 0, stream>>>(Sb);

  // ctx = P @ V : kt = 4*(br+1) causal truncation; ctx into Xb region
  gemm8<0, 0><<<dim3(8, 4, 8), 512, 0, stream>>>(
      Sb, 2048, 4194304LL, Vt, 2048, 2097152LL,
      ctx, 1024, 2097152LL, nullptr, 0, 1.0f, 4, 4, nullptr);

  // out = ctx @ Wo + bo (fp32 epilogue to d_out), A-stripe swizzle
  gemm8<1, 1><<<dim3(64, 4, 1), 512, 0, stream>>>(
      ctx, 1024, 0LL, Wt + 3 * 1048576, 1024, 0LL,
      d_out, 1024, 0LL, bo, 0, 1.0f, 16, 0, nullptr);
}